// Round 11
// baseline (168.864 us; speedup 1.0000x reference)
//
#include <hip/hip_runtime.h>
#include <hip/hip_bf16.h>
#include <stdint.h>

// Problem constants (from reference)
#define N1 8
#define N2 8
#define PP 1024
#define DD 768
#define PH 32
#define PW 32
#define OH 512
#define OW 512

#define NKT 6    // 768 / 128 K-tiles (BK=128 i8 elements = 128-B rows)

typedef int i32x4 __attribute__((ext_vector_type(4)));
typedef int i32x16 __attribute__((ext_vector_type(16)));

// ---------------- K1: row L2-normalize f32 -> i8 (q = round(127*x/||x||)) --
// Verified R7/R8/R9: final absmax 3.9e-3 vs threshold 1.35e-2.
__global__ __launch_bounds__(256) void nrm_kernel(
    const float* __restrict__ inA, const float* __restrict__ inB,
    char* __restrict__ outA, char* __restrict__ outB) {
  int row = blockIdx.x;
  const float* src;
  char* dst;
  if (row < N1 * PP) {
    src = inA + (size_t)row * DD;
    dst = outA + (size_t)row * DD;
  } else {
    row -= N1 * PP;
    src = inB + (size_t)row * DD;
    dst = outB + (size_t)row * DD;
  }
  const int t = threadIdx.x;
  const float v0 = src[t], v1 = src[t + 256], v2 = src[t + 512];
  float s = v0 * v0 + v1 * v1 + v2 * v2;
#pragma unroll
  for (int m = 32; m; m >>= 1) s += __shfl_xor(s, m, 64);
  __shared__ float red[4];
  const int wave = t >> 6, lane = t & 63;
  if (lane == 0) red[wave] = s;
  __syncthreads();
  const float inv = 127.0f / sqrtf(red[0] + red[1] + red[2] + red[3]);
  dst[t]       = (char)__float2int_rn(v0 * inv);
  dst[t + 256] = (char)__float2int_rn(v1 * inv);
  dst[t + 512] = (char)__float2int_rn(v2 * inv);
}

__device__ __forceinline__ void gll16(const char* src, char* dst) {
  __builtin_amdgcn_global_load_lds(
      (const __attribute__((address_space(1))) void*)src,
      (__attribute__((address_space(3))) void*)dst, 16, 0, 0);
}

// -------- K2: i8 gram row-max, 256x256, BK=128, 2-slot drift, MFMA 32x32 ---
// R10: single change vs R9 = mfma_i32_32x32x32_i8 (m55: 4404 TOPS vs 3944,
// half the MFMA instructions at identical LDS-read counts/bytes). Splits the
// "MFMA-issue vs LDS-read bound" models at constant memory behavior.
// 8 waves (2M x 4N), per-wave C = 128x64 = 4x2 blocks of 32x32, acc[4][2]
// i32x16 (128 regs, same as R9).
// LDS: 2 slots x {A,B} x [256 rows][128 B] = 128 KiB. Staging identical R9.
// Per iter k: stage kt k+1 (8 gll16) -> 4 kk-groups of {6 ds_read_b128 +
// 8 MFMA} -> vmcnt(0) -> ONE barrier. No setprio (m190).
// Swizzle (R7/R8/R9-verified, 0 conflicts): LDS byte y holds global byte
// S(y) = y ^ (((y>>7)&7)<<4). Operand row for 32x32 = lane&31 -> row&7 ==
// lane&7 (m*32, n*32, wr*128, wc*64 all 0 mod 8) -> lane-constant XOR.
// col = kk*32 + (lane>>5)*16: bits 4-6 only; XOR bits 4-6 -> carry-free.
__global__ __launch_bounds__(512, 2) void grami8_kernel(
    const char* __restrict__ fq, const char* __restrict__ gq,
    int* __restrict__ rowmaxI) {
  __shared__ __align__(16) char lds[2][2][32768];  // [slot][A,B][256*128]

  // XCD swizzle: 1024 wgs, 128 contiguous per XCD (bijective, 1024%8==0).
  const int bid = blockIdx.x;
  const int wg = (bid & 7) * 128 + (bid >> 3);
  const int pair = wg >> 4;                 // 0..63
  const int tile = wg & 15;
  const int fn = pair >> 3, gm = pair & 7;
  const int mt = tile >> 2, nt = tile & 3;  // 4x4 tiles of 256x256
  const int brow = mt * 256, bcol = nt * 256;

  const int t = threadIdx.x;
  const int lane = t & 63, wave = t >> 6;
  const int l31 = lane & 31, hi = lane >> 5;
  const int wr = wave >> 2, wc = wave & 3;  // 2M x 4N, per-wave 128x64

  const char* rowA = fq + ((size_t)fn * PP + brow) * DD;
  const char* rowB = gq + ((size_t)gm * PP + bcol) * DD;

  // Staging source mapping (R9-verified): chunk c (0..2047) of a 32-KB buf
  // holds global bytes S(c*16): x = c*16 ^ (((c>>3)&7)<<4).
  int srow[4], scol[4];
#pragma unroll
  for (int j = 0; j < 4; ++j) {
    const int c = t + j * 512;
    const int x = (c * 16) ^ (((c >> 3) & 7) << 4);
    srow[j] = x >> 7;
    scol[j] = x & 127;
  }

  // Fragment read byte offsets (32x32 operand layout: row = blk*32 + l31,
  // 16 B at col = kk*32 + hi*16, XOR'd with ((row&7)<<4) == ((lane&7)<<4)).
  const int swzm = (lane & 7) << 4;
  int fkk[4];
#pragma unroll
  for (int kk = 0; kk < 4; ++kk)
    fkk[kk] = (kk * 32 + hi * 16) ^ swzm;
  const int abase = (wr * 128 + l31) * 128;   // + m*32*128 + fkk
  const int bbase = (wc * 64 + l31) * 128;    // + n*32*128 + fkk

#define STAGE(rowPtr, kt, slot, mat)                                       \
  do {                                                                     \
    _Pragma("unroll")                                                      \
    for (int j = 0; j < 4; ++j)                                            \
      gll16(rowPtr + (size_t)srow[j] * DD + (kt) * 128 + scol[j],          \
            &lds[slot][mat][(t + j * 512) * 16]);                          \
  } while (0)

  i32x16 acc[4][2];
#pragma unroll
  for (int i = 0; i < 4; ++i)
#pragma unroll
    for (int j = 0; j < 2; ++j)
#pragma unroll
      for (int e = 0; e < 16; ++e) acc[i][j][e] = 0;

  // Prologue: stage kt 0 into slot 0.
  STAGE(rowB, 0, 0, 1);
  STAGE(rowA, 0, 0, 0);
  asm volatile("s_waitcnt vmcnt(0)" ::: "memory");
  __builtin_amdgcn_s_barrier();
  asm volatile("" ::: "memory");

#pragma unroll 1
  for (int k = 0; k < NKT; ++k) {
    const char* Ab = &lds[k & 1][0][0];
    const char* Bb = &lds[k & 1][1][0];

    // Stage kt k+1 into the other slot (issued early; lands under MFMA).
    if (k + 1 < NKT) {
      const int ns = (k + 1) & 1;
      STAGE(rowB, k + 1, ns, 1);
      STAGE(rowA, k + 1, ns, 0);
    }

    // 4 kk-groups: {4 A-reads + 2 B-reads + 8 MFMA 32x32x32}.
#pragma unroll
    for (int kk = 0; kk < 4; ++kk) {
      i32x4 a[4], b[2];
#pragma unroll
      for (int m = 0; m < 4; ++m)
        a[m] = *(const i32x4*)(Ab + abase + m * 32 * 128 + fkk[kk]);
#pragma unroll
      for (int n = 0; n < 2; ++n)
        b[n] = *(const i32x4*)(Bb + bbase + n * 32 * 128 + fkk[kk]);
#pragma unroll
      for (int m = 0; m < 4; ++m)
#pragma unroll
        for (int n = 0; n < 2; ++n)
          acc[m][n] = __builtin_amdgcn_mfma_i32_32x32x32_i8(a[m], b[n],
                                                            acc[m][n], 0, 0, 0);
    }

    // Slot k+1 resident before next iter; loads issued a full iter ago.
    asm volatile("s_waitcnt vmcnt(0)" ::: "memory");
    __builtin_amdgcn_s_barrier();
    asm volatile("" ::: "memory");
  }

  // Row-max epilogue. 32x32 C/D layout (m74/m101): col = lane&31,
  // row = (reg&3) + 8*(reg>>2) + 4*(lane>>5). Lanes 0-31 share one p-row
  // per reg (hi=0), lanes 32-63 the p+4 row; reduce over q = lanes within
  // each 32-half (shfl_xor 1..16 stays in-half), max over the 2 n-blocks.
  int* rm = rowmaxI + (size_t)(fn * 8 + gm) * PP;
#pragma unroll
  for (int m = 0; m < 4; ++m) {
#pragma unroll
    for (int r = 0; r < 16; ++r) {
      int vv = max(acc[m][0][r], acc[m][1][r]);
      vv = max(vv, __shfl_xor(vv, 1, 64));
      vv = max(vv, __shfl_xor(vv, 2, 64));
      vv = max(vv, __shfl_xor(vv, 4, 64));
      vv = max(vv, __shfl_xor(vv, 8, 64));
      vv = max(vv, __shfl_xor(vv, 16, 64));
      if (l31 == 0) {
        const int row = brow + wr * 128 + m * 32 + (r & 3) + 8 * (r >> 2) + 4 * hi;
        atomicMax(&rm[row], vv);
      }
    }
  }
#undef STAGE
}

// ---------------- K3: rowmax(i32) -> dist -> scores + sp ----------------
__global__ __launch_bounds__(256) void finalize_kernel(
    const int* __restrict__ rowmaxI, float* __restrict__ sp,
    float* __restrict__ scores) {
  const int n = blockIdx.x, t = threadIdx.x;
  const int lane = t & 63, wave = t >> 6;
  __shared__ float red[4];
  __shared__ float maxd[N2];
  float spacc[4] = {0.f, 0.f, 0.f, 0.f};
  for (int m = 0; m < N2; ++m) {
    float lmax = -1e30f;
#pragma unroll
    for (int i = 0; i < 4; ++i) {
      const int p = t + i * 256;
      const float g = (float)rowmaxI[(size_t)(n * N2 + m) * PP + p] *
                      (1.0f / 16129.0f);  // 127^2
      const float d = 0.5f * sqrtf(fmaxf(0.f, 2.f - 2.f * g));
      spacc[i] += d;
      lmax = fmaxf(lmax, d);
    }
#pragma unroll
    for (int msk = 32; msk; msk >>= 1) lmax = fmaxf(lmax, __shfl_xor(lmax, msk, 64));
    if (lane == 0) red[wave] = lmax;
    __syncthreads();
    if (t == 0) maxd[m] = fmaxf(fmaxf(red[0], red[1]), fmaxf(red[2], red[3]));
    __syncthreads();
  }
  if (t == 0) {
    float s = 0.f;
    for (int m = 0; m < N2; ++m) s += maxd[m];
    scores[n] = s * (1.0f / N2);
  }
#pragma unroll
  for (int i = 0; i < 4; ++i)
    sp[(size_t)n * PP + t + i * 256] = spacc[i] * (1.0f / N2);
}

// ---------------- K4: bilinear resize 32x32 -> 512x512 ----------------
__global__ __launch_bounds__(256) void resize_kernel(
    const float* __restrict__ sp, float* __restrict__ out) {
  const int idx = blockIdx.x * 256 + threadIdx.x;
  const int ox = idx & (OW - 1);
  const int oy = (idx >> 9) & (OH - 1);
  const int n = idx >> 18;
  const float sy = (oy + 0.5f) * ((float)PH / OH) - 0.5f;
  const float sx = (ox + 0.5f) * ((float)PW / OW) - 0.5f;
  const float y0f = floorf(sy), x0f = floorf(sx);
  const float wy = sy - y0f, wx = sx - x0f;
  int y0 = (int)y0f, x0 = (int)x0f;
  int y1 = y0 + 1, x1 = x0 + 1;
  y0 = min(max(y0, 0), PH - 1);
  y1 = min(max(y1, 0), PH - 1);
  x0 = min(max(x0, 0), PW - 1);
  x1 = min(max(x1, 0), PW - 1);
  const float* s = sp + (size_t)n * PP;
  const float v00 = s[y0 * PW + x0], v01 = s[y0 * PW + x1];
  const float v10 = s[y1 * PW + x0], v11 = s[y1 * PW + x1];
  const float top = v00 * (1.f - wx) + v01 * wx;
  const float bot = v10 * (1.f - wx) + v11 * wx;
  out[idx] = top * (1.f - wy) + bot * wy;
}

extern "C" void kernel_launch(void* const* d_in, const int* in_sizes, int n_in,
                              void* d_out, int out_size, void* d_ws, size_t ws_size,
                              hipStream_t stream) {
  const float* feats = (const float*)d_in[0];
  const float* nfeats = (const float*)d_in[1];
  float* out = (float*)d_out;

  char* ws = (char*)d_ws;
  const size_t FQ_BYTES = (size_t)N1 * PP * DD;  // 6,291,456
  char* fq = ws;
  char* gq = ws + FQ_BYTES;
  int* rowmaxI = (int*)(ws + 2 * FQ_BYTES);
  float* sp = (float*)(ws + 2 * FQ_BYTES + (size_t)N1 * N2 * PP * 4);

  // rowmax sentinel: 0x80808080 = -2139062144 < -768*127^2 (min possible dot)
  hipMemsetAsync(rowmaxI, 0x80, (size_t)N1 * N2 * PP * 4, stream);

  nrm_kernel<<<(N1 + N2) * PP, 256, 0, stream>>>(feats, nfeats, fq, gq);

  grami8_kernel<<<1024, 512, 0, stream>>>(fq, gq, rowmaxI);

  finalize_kernel<<<N1, 256, 0, stream>>>(rowmaxI, sp, out);
  resize_kernel<<<(N1 * OH * OW) / 256, 256, 0, stream>>>(sp, out + 8);
}